// Round 10
// baseline (202.455 us; speedup 1.0000x reference)
//
#include <hip/hip_runtime.h>

#define B_ 4
#define C_ 256
#define N_ 4096
#define K2_ 0.09016844f   /* 0.0625 * log2(e) */
#define THR_ 64.0f        /* defer-max threshold, raw-score units */

typedef __attribute__((ext_vector_type(8))) short short8;
typedef __attribute__((ext_vector_type(4))) float f32x4;
typedef __attribute__((ext_vector_type(16))) float f32x16;
typedef __attribute__((ext_vector_type(4))) unsigned int uint4v;

static __device__ __forceinline__ short f2bf(float f) {
  union { float f; unsigned u; } v; v.f = f;
  unsigned r = v.u + 0x7FFFu + ((v.u >> 16) & 1u);
  return (short)(r >> 16);
}
static __device__ __forceinline__ float bf2f(short s) {
  union { unsigned u; float f; } v; v.u = ((unsigned)(unsigned short)s) << 16;
  return v.f;
}
static __device__ __forceinline__ f32x4 mfma16(short8 a, short8 b, f32x4 c) {
  return __builtin_amdgcn_mfma_f32_16x16x32_bf16(a, b, c, 0, 0, 0);
}
static __device__ __forceinline__ f32x16 mfma32(short8 a, short8 b, f32x16 c) {
  return __builtin_amdgcn_mfma_f32_32x32x16_bf16(a, b, c, 0, 0, 0);
}
static __device__ __forceinline__ unsigned cvtpk(float lo, float hi) {
  unsigned r;
  asm("v_cvt_pk_bf16_f32 %0, %1, %2" : "=v"(r) : "v"(lo), "v"(hi));
  return r;
}
static __device__ __forceinline__ void plswap(unsigned& a, unsigned& b) {
  asm volatile("v_permlane32_swap_b32 %0, %1" : "+v"(a), "+v"(b));
}
static __device__ __forceinline__ void gload16(const void* g, void* l) {
  __builtin_amdgcn_global_load_lds(
      (const __attribute__((address_space(1))) unsigned int*)g,
      (__attribute__((address_space(3))) unsigned int*)l, 16, 0, 0);
}

// ---------------- GroupNorm stats (split 4-way per group) ----------------
__global__ __launch_bounds__(256) void gn_stats1(const float* __restrict__ x,
                                                 float2* __restrict__ part) {
  int bg = blockIdx.x >> 2, ch = blockIdx.x & 3;
  const float* xp = x + (long)bg * 65536 + ch * 16384;
  int t = threadIdx.x, lane = t & 63, w = t >> 6;
  float s = 0.f, ss = 0.f;
  for (int e = t * 4; e < 16384; e += 1024) {
    f32x4 v = *(const f32x4*)(xp + e);
    s += (v[0] + v[1]) + (v[2] + v[3]);
    ss += (v[0] * v[0] + v[1] * v[1]) + (v[2] * v[2] + v[3] * v[3]);
  }
  for (int off = 1; off < 64; off <<= 1) {
    s += __shfl_xor(s, off);
    ss += __shfl_xor(ss, off);
  }
  __shared__ float rs[4], rq[4];
  if (lane == 0) { rs[w] = s; rq[w] = ss; }
  __syncthreads();
  if (t == 0)
    part[blockIdx.x] = make_float2((rs[0] + rs[1]) + (rs[2] + rs[3]),
                                   (rq[0] + rq[1]) + (rq[2] + rq[3]));
}

// writes hn transposed: hn[b][i][c] bf16
__global__ __launch_bounds__(256) void gn_norm(const float* __restrict__ x,
                                               const float* __restrict__ gamma,
                                               const float* __restrict__ beta,
                                               const float2* __restrict__ part,
                                               short* __restrict__ hn) {
  int ic = blockIdx.x, g = blockIdx.y, b = blockIdx.z;
  int bg = b * 16 + g;
  float2 q0 = part[bg * 4], q1 = part[bg * 4 + 1], q2 = part[bg * 4 + 2], q3 = part[bg * 4 + 3];
  float s = (q0.x + q1.x) + (q2.x + q3.x);
  float ss = (q0.y + q1.y) + (q2.y + q3.y);
  float mean = s * (1.f / 65536.f);
  float rstd = rsqrtf(ss * (1.f / 65536.f) - mean * mean + 1e-6f);
  int t = threadIdx.x;
  int i = ic * 256 + t;
  __shared__ short Ls[16][256];
#pragma unroll
  for (int cl = 0; cl < 16; cl++) {
    int c = g * 16 + cl;
    float v = x[((long)(b * 256 + c)) * N_ + i];
    Ls[cl][t] = f2bf((v - mean) * rstd * gamma[c] + beta[c]);
  }
  __syncthreads();
  short8 v0, v1;
#pragma unroll
  for (int q = 0; q < 8; q++) { v0[q] = Ls[q][t]; v1[q] = Ls[8 + q][t]; }
  short* dst = hn + ((long)b * N_ + ic * 256 + t) * C_ + g * 16;
  *(short8*)dst = v0;
  *(short8*)(dst + 8) = v1;
}

// ---------------- weight cast ----------------
__global__ __launch_bounds__(256) void cast_w(const float* __restrict__ wq,
                                              const float* __restrict__ wk,
                                              const float* __restrict__ wv,
                                              const float* __restrict__ wp,
                                              short* __restrict__ out) {
  int idx = blockIdx.x * 256 + threadIdx.x;
  int which = idx >> 16, e = idx & 65535;
  const float* src = which == 0 ? wq : which == 1 ? wk : which == 2 ? wv : wp;
  out[(which << 16) + e] = f2bf(src[e]);
}

// ---------------- fused QKV GEMM (triple-buffer, counted vmcnt) ----------------
__global__ __launch_bounds__(256) void gemm_qkv(const short* __restrict__ hn,
                                                const short* __restrict__ wqkv,
                                                const float* __restrict__ bq,
                                                const float* __restrict__ bk,
                                                const float* __restrict__ bv,
                                                short* __restrict__ qT,
                                                short* __restrict__ kT,
                                                short* __restrict__ vbM) {
  __shared__ __align__(16) short As[3][128 * 32];
  __shared__ __align__(16) short Bs[3][128 * 32];
  const int bz = blockIdx.z;
  const int n0 = blockIdx.x * 128;   // within 768
  const int m0 = blockIdx.y * 128;   // within 4096
  const int t = threadIdx.x, lane = t & 63, w = t >> 6;
  const int wm = (w >> 1) * 64, wn = (w & 1) * 64;
  const short* Ab = hn + (long)bz * N_ * C_;
  f32x4 acc[4][4];
#pragma unroll
  for (int m = 0; m < 4; m++)
#pragma unroll
    for (int n = 0; n < 4; n++) acc[m][n] = (f32x4)0.f;
  const int g16 = (lane >> 4) * 16;

  auto stage = [&](int kt8, int buf) {
    int kt = kt8 * 32;
#pragma unroll
    for (int s = 0; s < 2; s++) {
      int q = w * 2 + s;
      int flat = q * 1024 + lane * 16;
      int row = flat >> 6, c = flat & 63;
      int cs = c ^ ((row & 3) << 4);
      gload16((const char*)Ab + ((long)(m0 + row) * 256 + kt) * 2 + cs, (char*)As[buf] + flat);
      gload16((const char*)wqkv + ((long)(n0 + row) * 256 + kt) * 2 + cs, (char*)Bs[buf] + flat);
    }
  };

  stage(0, 0);
  for (int kt8 = 0; kt8 < 8; kt8++) {
    const int cur = kt8 % 3;
    if (kt8 < 7) {
      stage(kt8 + 1, (kt8 + 1) % 3);
      asm volatile("s_waitcnt vmcnt(4)" ::: "memory");
    } else {
      asm volatile("s_waitcnt vmcnt(0)" ::: "memory");
    }
    __builtin_amdgcn_s_barrier();
    __builtin_amdgcn_sched_barrier(0);
    short8 af[4], bf[4];
#pragma unroll
    for (int m = 0; m < 4; m++) {
      int row = wm + m * 16 + (lane & 15);
      af[m] = *(const short8*)(&As[cur][0] + row * 32 + ((g16 ^ ((row & 3) << 4)) >> 1));
    }
#pragma unroll
    for (int n = 0; n < 4; n++) {
      int row = wn + n * 16 + (lane & 15);
      bf[n] = *(const short8*)(&Bs[cur][0] + row * 32 + ((g16 ^ ((row & 3) << 4)) >> 1));
    }
    __builtin_amdgcn_s_setprio(1);
#pragma unroll
    for (int m = 0; m < 4; m++)
#pragma unroll
      for (int n = 0; n < 4; n++) acc[m][n] = mfma16(af[m], bf[n], acc[m][n]);
    __builtin_amdgcn_s_setprio(0);
  }

  int seg = n0 >> 8;
  const float* bias = seg == 0 ? bq : seg == 1 ? bk : bv;
#pragma unroll
  for (int m = 0; m < 4; m++)
#pragma unroll
    for (int n = 0; n < 4; n++)
#pragma unroll
      for (int r = 0; r < 4; r++) {
        int row = m0 + wm + m * 16 + ((lane >> 4) << 2) + r;
        int colg = n0 + wn + n * 16 + (lane & 15);
        int coll = colg & 255;
        float vv = acc[m][n][r] + bias[coll];
        if (seg == 2) vbM[(long)bz * N_ * C_ + (long)coll * N_ + row] = f2bf(vv);
        else (seg == 0 ? qT : kT)[(long)bz * N_ * C_ + (long)row * 256 + coll] = f2bf(vv);
      }
}

// ---------------- output projection GEMM (triple-buffer, counted vmcnt) --------
__global__ __launch_bounds__(256) void gemm_proj(const short* __restrict__ wp,
                                                 const short* __restrict__ hT,
                                                 const float* __restrict__ bp,
                                                 const float* __restrict__ x,
                                                 float* __restrict__ out) {
  __shared__ __align__(16) short As[3][128 * 32];
  __shared__ __align__(16) short Bs[3][128 * 32];
  const int bz = blockIdx.z;
  const int n0 = blockIdx.x * 128;   // pixels
  const int m0 = blockIdx.y * 128;   // channels
  const int t = threadIdx.x, lane = t & 63, w = t >> 6;
  const int wm = (w >> 1) * 64, wn = (w & 1) * 64;
  const short* Bb = hT + (long)bz * N_ * C_;
  f32x4 acc[4][4];
#pragma unroll
  for (int m = 0; m < 4; m++)
#pragma unroll
    for (int n = 0; n < 4; n++) acc[m][n] = (f32x4)0.f;
  const int g16 = (lane >> 4) * 16;

  auto stage = [&](int kt8, int buf) {
    int kt = kt8 * 32;
#pragma unroll
    for (int s = 0; s < 2; s++) {
      int q = w * 2 + s;
      int flat = q * 1024 + lane * 16;
      int row = flat >> 6, c = flat & 63;
      int cs = c ^ ((row & 3) << 4);
      gload16((const char*)wp + ((long)(m0 + row) * 256 + kt) * 2 + cs, (char*)As[buf] + flat);
      gload16((const char*)Bb + ((long)(n0 + row) * 256 + kt) * 2 + cs, (char*)Bs[buf] + flat);
    }
  };

  stage(0, 0);
  for (int kt8 = 0; kt8 < 8; kt8++) {
    const int cur = kt8 % 3;
    if (kt8 < 7) {
      stage(kt8 + 1, (kt8 + 1) % 3);
      asm volatile("s_waitcnt vmcnt(4)" ::: "memory");
    } else {
      asm volatile("s_waitcnt vmcnt(0)" ::: "memory");
    }
    __builtin_amdgcn_s_barrier();
    __builtin_amdgcn_sched_barrier(0);
    short8 af[4], bf[4];
#pragma unroll
    for (int m = 0; m < 4; m++) {
      int row = wm + m * 16 + (lane & 15);
      af[m] = *(const short8*)(&As[cur][0] + row * 32 + ((g16 ^ ((row & 3) << 4)) >> 1));
    }
#pragma unroll
    for (int n = 0; n < 4; n++) {
      int row = wn + n * 16 + (lane & 15);
      bf[n] = *(const short8*)(&Bs[cur][0] + row * 32 + ((g16 ^ ((row & 3) << 4)) >> 1));
    }
    __builtin_amdgcn_s_setprio(1);
#pragma unroll
    for (int m = 0; m < 4; m++)
#pragma unroll
      for (int n = 0; n < 4; n++) acc[m][n] = mfma16(af[m], bf[n], acc[m][n]);
    __builtin_amdgcn_s_setprio(0);
  }

#pragma unroll
  for (int m = 0; m < 4; m++)
#pragma unroll
    for (int n = 0; n < 4; n++)
#pragma unroll
      for (int r = 0; r < 4; r++) {
        int row = m0 + wm + m * 16 + ((lane >> 4) << 2) + r;   // channel
        int col = n0 + wn + n * 16 + (lane & 15);              // pixel
        long idx = (long)bz * N_ * C_ + (long)row * N_ + col;
        out[idx] = acc[m][n][r] + bp[row] + x[idx];
      }
}

// ---------------- flash attention: 4 waves, 128 rows, KVBLK=32, K+V dbuf ------
// LDS: kv[2][32KB]: per buf K 16KB @0, V 16KB @16384. ONE barrier per iter:
//   stage(it+1 -> buf^1) ; QK(it) ; SM(it) ; PV(it) ; __syncthreads()
// Barrier both drains stage(it+1) and protects buf(it) before it+2 overwrites it.
// K tile: [32 j][512B], byte col ^ ((j&31)<<4)           -> 0-conflict QK reads
// V tile: [32 rows][512B], row=c&31, col=(c>>5)*64+j*2, same XOR -> 0-conflict PV
__global__ __launch_bounds__(256, 2) void attn_kernel(
    const short* __restrict__ qT, const short* __restrict__ kT,
    const short* __restrict__ vM, short* __restrict__ P0, short* __restrict__ P1,
    short* __restrict__ P2, short* __restrict__ P3, float2* __restrict__ ml, int S) {
  __shared__ __align__(16) char kv[2][32768];
  __shared__ float cbr[4][32];

  const int nwg = 128 * S;                      // 512 at S=4
  const int id = blockIdx.x;
  const int nid = (id & 7) * (nwg >> 3) + (id >> 3);  // XCD-contiguous (bijective, nwg%8==0)
  const int itile = nid & 31;                   // 32 itiles x 128 rows
  const int bjs = nid >> 5;
  const int js = bjs % S;
  const int b = bjs / S;

  const int t = threadIdx.x, lane = t & 63, w = t >> 6;   // w: 0..3
  const int hi = lane >> 5, li = lane & 31;
  const int hi16 = hi * 16;
  const int lsw = li << 4;
  const long bNC = (long)b * N_ * C_;
  const short* qb = qT + bNC;
  const char* kb = (const char*)(kT + bNC);
  const char* vbp = (const char*)(vM + bNC);
  const int i0 = itile * 128 + w * 32;
  const int jbase = js * (N_ / S);
  const int NIT = (N_ / S) / 32;                // 32 when S=4

  // Q b-frags: qf[s] = Q[i0+li][s*16 + hi*8 .. +8]
  short8 qf[16];
  {
    const short* qp = qb + (long)(i0 + li) * C_ + hi * 8;
#pragma unroll
    for (int s = 0; s < 16; s++) qf[s] = *(const short8*)(qp + s * 16);
  }

  f32x16 acco[8];
#pragma unroll
  for (int cb = 0; cb < 8; cb++) acco[cb] = (f32x16)0.f;
  float m_run = -3e38f, l_run = 0.f;

  auto stage = [&](int it, int buf) {
    const int j0 = jbase + it * 32;
    char* Kd = kv[buf];
    char* Vd = kv[buf] + 16384;
#pragma unroll
    for (int p = 0; p < 4; p++) {
      int flat = p * 4096 + t * 16;
      int rk = flat >> 9;
      int cO = (flat & 511) ^ ((rk & 31) << 4);
      gload16(kb + (long)(j0 + rk) * 512 + cO, Kd + flat);
    }
#pragma unroll
    for (int p = 0; p < 4; p++) {
      int flat = p * 4096 + t * 16;
      int rv = flat >> 9;
      int cO = (flat & 511) ^ ((rv & 31) << 4);
      int c = rv + ((cO >> 6) << 5);
      int off = cO & 63;
      gload16(vbp + (long)c * 8192 + (long)j0 * 2 + off, Vd + flat);
    }
  };

  auto smpack = [&](f32x16& accs, short8& paA, short8& paB) {
    float pmax = accs[0];
#pragma unroll
    for (int r = 1; r < 16; r++) pmax = fmaxf(pmax, accs[r]);
    pmax = fmaxf(pmax, __shfl_xor(pmax, 32));
    if (__any(pmax > m_run + THR_)) {
      float mnew = fmaxf(m_run, pmax);
      float corr = exp2f((m_run - mnew) * K2_);
      m_run = mnew;
      l_run *= corr;
      if (lane < 32) cbr[w][li] = corr;
      asm volatile("s_waitcnt lgkmcnt(0)" ::: "memory");
      f32x4 c4[4];
#pragma unroll
      for (int g = 0; g < 4; g++) c4[g] = *(const f32x4*)&cbr[w][g * 8 + hi * 4];
#pragma unroll
      for (int cb = 0; cb < 8; cb++)
#pragma unroll
        for (int r = 0; r < 16; r++) acco[cb][r] *= c4[r >> 2][r & 3];
    }
    const float mk = m_run * K2_;
    float p[16];
#pragma unroll
    for (int r = 0; r < 16; r++) {
      p[r] = exp2f(fmaf(accs[r], K2_, -mk));
      l_run += p[r];
    }
    unsigned a0 = cvtpk(p[0], p[1]), b0 = cvtpk(p[4], p[5]);
    unsigned a1 = cvtpk(p[2], p[3]), b1 = cvtpk(p[6], p[7]);
    plswap(a0, b0); plswap(a1, b1);
    uint4v u0 = {a0, a1, b0, b1};
    paA = __builtin_bit_cast(short8, u0);
    unsigned a2 = cvtpk(p[8], p[9]), b2 = cvtpk(p[12], p[13]);
    unsigned a3 = cvtpk(p[10], p[11]), b3 = cvtpk(p[14], p[15]);
    plswap(a2, b2); plswap(a3, b3);
    uint4v u1 = {a2, a3, b2, b3};
    paB = __builtin_bit_cast(short8, u1);
  };

  stage(0, 0);
  __syncthreads();

  for (int it = 0; it < NIT; it++) {
    const int cur = it & 1;
    if (it + 1 < NIT) stage(it + 1, cur ^ 1);
    const char* Kr = kv[cur] + li * 512;
    const char* Vr = kv[cur] + 16384 + li * 512;

    // QK(it): two independent accumulator chains
    f32x16 ae = (f32x16)0.f, ao = (f32x16)0.f;
    __builtin_amdgcn_s_setprio(1);
#pragma unroll
    for (int u = 0; u < 8; u++) {
      short8 k0 = *(const short8*)(Kr + (((2 * u) * 32 + hi16) ^ lsw));
      ae = mfma32(k0, qf[2 * u], ae);
      short8 k1 = *(const short8*)(Kr + (((2 * u + 1) * 32 + hi16) ^ lsw));
      ao = mfma32(k1, qf[2 * u + 1], ao);
    }
    __builtin_amdgcn_s_setprio(0);
    f32x16 accs = ae + ao;

    short8 pa0, pa1;
    smpack(accs, pa0, pa1);

    // PV(it)
    __builtin_amdgcn_s_setprio(1);
#pragma unroll
    for (int cb = 0; cb < 8; cb++) {
      short8 vf0 = *(const short8*)(Vr + ((cb * 64 + hi16) ^ lsw));
      acco[cb] = mfma32(pa0, vf0, acco[cb]);
      short8 vf1 = *(const short8*)(Vr + ((cb * 64 + 32 + hi16) ^ lsw));
      acco[cb] = mfma32(pa1, vf1, acco[cb]);
    }
    __builtin_amdgcn_s_setprio(0);
    __syncthreads();
  }

  // finalize: total l, broadcast 1/l per row, store normalized partial + (m,l)
  l_run += __shfl_xor(l_run, 32);
  float inv = 1.f / l_run;
  if (lane < 32) cbr[w][li] = inv;
  asm volatile("s_waitcnt lgkmcnt(0)" ::: "memory");
  f32x4 i4[4];
#pragma unroll
  for (int g = 0; g < 4; g++) i4[g] = *(const f32x4*)&cbr[w][g * 8 + hi * 4];

  short* Op = (js == 0) ? P0 : (js == 1) ? P1 : (js == 2) ? P2 : P3;
  short* ob = Op + bNC;
#pragma unroll
  for (int cb = 0; cb < 8; cb++)
#pragma unroll
    for (int r = 0; r < 16; r++) {
      int i = i0 + (r & 3) + 8 * (r >> 2) + 4 * hi;
      ob[(long)i * C_ + cb * 32 + li] = f2bf(acco[cb][r] * i4[r >> 2][r & 3]);
    }
  if (lane < 32)
    ml[(long)js * (B_ * N_) + b * N_ + i0 + li] = make_float2(m_run * K2_, l_run);
}

// ---------------- merge the split-j partials ----------------
__global__ __launch_bounds__(256) void combine(const short* __restrict__ p0,
                                               const short* __restrict__ p1,
                                               const short* __restrict__ p2,
                                               const short* __restrict__ p3,
                                               const float2* __restrict__ ml, int S,
                                               short* __restrict__ hT) {
  int idx = blockIdx.x * 256 + threadIdx.x;    // 16384 rows * 32 chunks
  int row = idx >> 5, c0 = (idx & 31) * 8;
  float2 m0 = ml[row], m1 = ml[16384 + row];
  float mmax = fmaxf(m0.x, m1.x);
  float2 m2 = m0, m3 = m0;
  if (S == 4) {
    m2 = ml[2 * 16384 + row];
    m3 = ml[3 * 16384 + row];
    mmax = fmaxf(mmax, fmaxf(m2.x, m3.x));
  }
  float w0 = m0.y * exp2f(m0.x - mmax);
  float w1 = m1.y * exp2f(m1.x - mmax);
  float w2 = 0.f, w3 = 0.f;
  if (S == 4) { w2 = m2.y * exp2f(m2.x - mmax); w3 = m3.y * exp2f(m3.x - mmax); }
  float inv = 1.f / ((w0 + w1) + (w2 + w3));
  w0 *= inv; w1 *= inv; w2 *= inv; w3 *= inv;
  long off = (long)row * 256 + c0;
  short8 u0 = *(const short8*)(p0 + off);
  short8 u1 = *(const short8*)(p1 + off);
  short8 o;
  if (S == 4) {
    short8 u2 = *(const short8*)(p2 + off);
    short8 u3 = *(const short8*)(p3 + off);
#pragma unroll
    for (int j = 0; j < 8; j++)
      o[j] = f2bf((w0 * bf2f(u0[j]) + w1 * bf2f(u1[j])) +
                  (w2 * bf2f(u2[j]) + w3 * bf2f(u3[j])));
  } else {
#pragma unroll
    for (int j = 0; j < 8; j++) o[j] = f2bf(w0 * bf2f(u0[j]) + w1 * bf2f(u1[j]));
  }
  *(short8*)(hT + off) = o;
}

// ---------------- launch ----------------
extern "C" void kernel_launch(void* const* d_in, const int* in_sizes, int n_in,
                              void* d_out, int out_size, void* d_ws, size_t ws_size,
                              hipStream_t stream) {
  const float* x = (const float*)d_in[0];
  const float* gamma = (const float*)d_in[1];
  const float* beta = (const float*)d_in[2];
  const float* wq = (const float*)d_in[3];
  const float* bq = (const float*)d_in[4];
  const float* wk = (const float*)d_in[5];
  const float* bk = (const float*)d_in[6];
  const float* wv = (const float*)d_in[7];
  const float* bv = (const float*)d_in[8];
  const float* wp = (const float*)d_in[9];
  const float* bp = (const float*)d_in[10];

  char* ws = (char*)d_ws;
  short* hn = (short*)ws;                                   // 8MB: hn -> partial0 -> hT
  short* qT = (short*)(ws + (size_t)8388608);
  short* kT = (short*)(ws + (size_t)16777216);
  short* vb = (short*)(ws + (size_t)25165824);
  short* wqkv = (short*)(ws + (size_t)33554432);            // [768][256]
  short* wpb = wqkv + 3 * 65536;                            // [256][256]
  float2* part = (float2*)(ws + (size_t)34078720);          // 256 float2
  float2* ml = (float2*)(ws + (size_t)34080768);            // up to 4*16384 float2
  short* P1 = (short*)d_out;                                // scratch (rewritten by gemm_proj)
  short* P2 = (short*)d_out + 4194304;
  short* P3 = (short*)(ws + (size_t)34605056);
  const int S = (ws_size >= (size_t)43000000) ? 4 : 2;
  if (S == 2) { P2 = hn; P3 = hn; }

  gn_stats1<<<256, 256, 0, stream>>>(x, part);
  gn_norm<<<dim3(16, 16, 4), 256, 0, stream>>>(x, gamma, beta, part, hn);
  cast_w<<<1024, 256, 0, stream>>>(wq, wk, wv, wp, wqkv);

  gemm_qkv<<<dim3(6, 32, 4), 256, 0, stream>>>(hn, wqkv, bq, bk, bv, qT, kT, vb);

  attn_kernel<<<dim3(128 * S), 256, 0, stream>>>(qT, kT, vb, hn /*P0*/, P1, P2, P3, ml, S);
  combine<<<2048, 256, 0, stream>>>(hn, P1, P2, P3, ml, S, hn /*hT in place*/);

  gemm_proj<<<dim3(32, 2, 4), 256, 0, stream>>>(wpb, hn, bp, x, (float*)d_out);
}

// Round 11
// 162.824 us; speedup vs baseline: 1.2434x; 1.2434x over previous
//
#include <hip/hip_runtime.h>

#define B_ 4
#define C_ 256
#define N_ 4096
#define K2_ 0.09016844f   /* 0.0625 * log2(e) */
#define THR_ 64.0f        /* defer-max threshold, raw-score units */

typedef __attribute__((ext_vector_type(8))) short short8;
typedef __attribute__((ext_vector_type(4))) float f32x4;
typedef __attribute__((ext_vector_type(16))) float f32x16;
typedef __attribute__((ext_vector_type(4))) unsigned int uint4v;

static __device__ __forceinline__ short f2bf(float f) {
  union { float f; unsigned u; } v; v.f = f;
  unsigned r = v.u + 0x7FFFu + ((v.u >> 16) & 1u);
  return (short)(r >> 16);
}
static __device__ __forceinline__ float bf2f(short s) {
  union { unsigned u; float f; } v; v.u = ((unsigned)(unsigned short)s) << 16;
  return v.f;
}
static __device__ __forceinline__ f32x4 mfma16(short8 a, short8 b, f32x4 c) {
  return __builtin_amdgcn_mfma_f32_16x16x32_bf16(a, b, c, 0, 0, 0);
}
static __device__ __forceinline__ f32x16 mfma32(short8 a, short8 b, f32x16 c) {
  return __builtin_amdgcn_mfma_f32_32x32x16_bf16(a, b, c, 0, 0, 0);
}
static __device__ __forceinline__ unsigned cvtpk(float lo, float hi) {
  unsigned r;
  asm("v_cvt_pk_bf16_f32 %0, %1, %2" : "=v"(r) : "v"(lo), "v"(hi));
  return r;
}
static __device__ __forceinline__ void plswap(unsigned& a, unsigned& b) {
  asm volatile("v_permlane32_swap_b32 %0, %1" : "+v"(a), "+v"(b));
}
static __device__ __forceinline__ void gload16(const void* g, void* l) {
  __builtin_amdgcn_global_load_lds(
      (const __attribute__((address_space(1))) unsigned int*)g,
      (__attribute__((address_space(3))) unsigned int*)l, 16, 0, 0);
}

// ---------------- GroupNorm stats (split 4-way per group) ----------------
__global__ __launch_bounds__(256) void gn_stats1(const float* __restrict__ x,
                                                 float2* __restrict__ part) {
  int bg = blockIdx.x >> 2, ch = blockIdx.x & 3;
  const float* xp = x + (long)bg * 65536 + ch * 16384;
  int t = threadIdx.x, lane = t & 63, w = t >> 6;
  float s = 0.f, ss = 0.f;
  for (int e = t * 4; e < 16384; e += 1024) {
    f32x4 v = *(const f32x4*)(xp + e);
    s += (v[0] + v[1]) + (v[2] + v[3]);
    ss += (v[0] * v[0] + v[1] * v[1]) + (v[2] * v[2] + v[3] * v[3]);
  }
  for (int off = 1; off < 64; off <<= 1) {
    s += __shfl_xor(s, off);
    ss += __shfl_xor(ss, off);
  }
  __shared__ float rs[4], rq[4];
  if (lane == 0) { rs[w] = s; rq[w] = ss; }
  __syncthreads();
  if (t == 0)
    part[blockIdx.x] = make_float2((rs[0] + rs[1]) + (rs[2] + rs[3]),
                                   (rq[0] + rq[1]) + (rq[2] + rq[3]));
}

// writes hn transposed: hn[b][i][c] bf16
__global__ __launch_bounds__(256) void gn_norm(const float* __restrict__ x,
                                               const float* __restrict__ gamma,
                                               const float* __restrict__ beta,
                                               const float2* __restrict__ part,
                                               short* __restrict__ hn) {
  int ic = blockIdx.x, g = blockIdx.y, b = blockIdx.z;
  int bg = b * 16 + g;
  float2 q0 = part[bg * 4], q1 = part[bg * 4 + 1], q2 = part[bg * 4 + 2], q3 = part[bg * 4 + 3];
  float s = (q0.x + q1.x) + (q2.x + q3.x);
  float ss = (q0.y + q1.y) + (q2.y + q3.y);
  float mean = s * (1.f / 65536.f);
  float rstd = rsqrtf(ss * (1.f / 65536.f) - mean * mean + 1e-6f);
  int t = threadIdx.x;
  int i = ic * 256 + t;
  __shared__ short Ls[16][256];
#pragma unroll
  for (int cl = 0; cl < 16; cl++) {
    int c = g * 16 + cl;
    float v = x[((long)(b * 256 + c)) * N_ + i];
    Ls[cl][t] = f2bf((v - mean) * rstd * gamma[c] + beta[c]);
  }
  __syncthreads();
  short8 v0, v1;
#pragma unroll
  for (int q = 0; q < 8; q++) { v0[q] = Ls[q][t]; v1[q] = Ls[8 + q][t]; }
  short* dst = hn + ((long)b * N_ + ic * 256 + t) * C_ + g * 16;
  *(short8*)dst = v0;
  *(short8*)(dst + 8) = v1;
}

// ---------------- weight cast ----------------
__global__ __launch_bounds__(256) void cast_w(const float* __restrict__ wq,
                                              const float* __restrict__ wk,
                                              const float* __restrict__ wv,
                                              const float* __restrict__ wp,
                                              short* __restrict__ out) {
  int idx = blockIdx.x * 256 + threadIdx.x;
  int which = idx >> 16, e = idx & 65535;
  const float* src = which == 0 ? wq : which == 1 ? wk : which == 2 ? wv : wp;
  out[(which << 16) + e] = f2bf(src[e]);
}

// ---------------- fused QKV GEMM (triple-buffer, counted vmcnt) ----------------
__global__ __launch_bounds__(256) void gemm_qkv(const short* __restrict__ hn,
                                                const short* __restrict__ wqkv,
                                                const float* __restrict__ bq,
                                                const float* __restrict__ bk,
                                                const float* __restrict__ bv,
                                                short* __restrict__ qT,
                                                short* __restrict__ kT,
                                                short* __restrict__ vbM) {
  __shared__ __align__(16) short As[3][128 * 32];
  __shared__ __align__(16) short Bs[3][128 * 32];
  const int bz = blockIdx.z;
  const int n0 = blockIdx.x * 128;   // within 768
  const int m0 = blockIdx.y * 128;   // within 4096
  const int t = threadIdx.x, lane = t & 63, w = t >> 6;
  const int wm = (w >> 1) * 64, wn = (w & 1) * 64;
  const short* Ab = hn + (long)bz * N_ * C_;
  f32x4 acc[4][4];
#pragma unroll
  for (int m = 0; m < 4; m++)
#pragma unroll
    for (int n = 0; n < 4; n++) acc[m][n] = (f32x4)0.f;
  const int g16 = (lane >> 4) * 16;

  auto stage = [&](int kt8, int buf) {
    int kt = kt8 * 32;
#pragma unroll
    for (int s = 0; s < 2; s++) {
      int q = w * 2 + s;
      int flat = q * 1024 + lane * 16;
      int row = flat >> 6, c = flat & 63;
      int cs = c ^ ((row & 3) << 4);
      gload16((const char*)Ab + ((long)(m0 + row) * 256 + kt) * 2 + cs, (char*)As[buf] + flat);
      gload16((const char*)wqkv + ((long)(n0 + row) * 256 + kt) * 2 + cs, (char*)Bs[buf] + flat);
    }
  };

  stage(0, 0);
  for (int kt8 = 0; kt8 < 8; kt8++) {
    const int cur = kt8 % 3;
    if (kt8 < 7) {
      stage(kt8 + 1, (kt8 + 1) % 3);
      asm volatile("s_waitcnt vmcnt(4)" ::: "memory");
    } else {
      asm volatile("s_waitcnt vmcnt(0)" ::: "memory");
    }
    __builtin_amdgcn_s_barrier();
    __builtin_amdgcn_sched_barrier(0);
    short8 af[4], bf[4];
#pragma unroll
    for (int m = 0; m < 4; m++) {
      int row = wm + m * 16 + (lane & 15);
      af[m] = *(const short8*)(&As[cur][0] + row * 32 + ((g16 ^ ((row & 3) << 4)) >> 1));
    }
#pragma unroll
    for (int n = 0; n < 4; n++) {
      int row = wn + n * 16 + (lane & 15);
      bf[n] = *(const short8*)(&Bs[cur][0] + row * 32 + ((g16 ^ ((row & 3) << 4)) >> 1));
    }
    __builtin_amdgcn_s_setprio(1);
#pragma unroll
    for (int m = 0; m < 4; m++)
#pragma unroll
      for (int n = 0; n < 4; n++) acc[m][n] = mfma16(af[m], bf[n], acc[m][n]);
    __builtin_amdgcn_s_setprio(0);
  }

  int seg = n0 >> 8;
  const float* bias = seg == 0 ? bq : seg == 1 ? bk : bv;
#pragma unroll
  for (int m = 0; m < 4; m++)
#pragma unroll
    for (int n = 0; n < 4; n++)
#pragma unroll
      for (int r = 0; r < 4; r++) {
        int row = m0 + wm + m * 16 + ((lane >> 4) << 2) + r;
        int colg = n0 + wn + n * 16 + (lane & 15);
        int coll = colg & 255;
        float vv = acc[m][n][r] + bias[coll];
        if (seg == 2) vbM[(long)bz * N_ * C_ + (long)coll * N_ + row] = f2bf(vv);
        else (seg == 0 ? qT : kT)[(long)bz * N_ * C_ + (long)row * 256 + coll] = f2bf(vv);
      }
}

// ---------------- output projection GEMM (triple-buffer, counted vmcnt) --------
__global__ __launch_bounds__(256) void gemm_proj(const short* __restrict__ wp,
                                                 const short* __restrict__ hT,
                                                 const float* __restrict__ bp,
                                                 const float* __restrict__ x,
                                                 float* __restrict__ out) {
  __shared__ __align__(16) short As[3][128 * 32];
  __shared__ __align__(16) short Bs[3][128 * 32];
  const int bz = blockIdx.z;
  const int n0 = blockIdx.x * 128;   // pixels
  const int m0 = blockIdx.y * 128;   // channels
  const int t = threadIdx.x, lane = t & 63, w = t >> 6;
  const int wm = (w >> 1) * 64, wn = (w & 1) * 64;
  const short* Bb = hT + (long)bz * N_ * C_;
  f32x4 acc[4][4];
#pragma unroll
  for (int m = 0; m < 4; m++)
#pragma unroll
    for (int n = 0; n < 4; n++) acc[m][n] = (f32x4)0.f;
  const int g16 = (lane >> 4) * 16;

  auto stage = [&](int kt8, int buf) {
    int kt = kt8 * 32;
#pragma unroll
    for (int s = 0; s < 2; s++) {
      int q = w * 2 + s;
      int flat = q * 1024 + lane * 16;
      int row = flat >> 6, c = flat & 63;
      int cs = c ^ ((row & 3) << 4);
      gload16((const char*)wp + ((long)(m0 + row) * 256 + kt) * 2 + cs, (char*)As[buf] + flat);
      gload16((const char*)Bb + ((long)(n0 + row) * 256 + kt) * 2 + cs, (char*)Bs[buf] + flat);
    }
  };

  stage(0, 0);
  for (int kt8 = 0; kt8 < 8; kt8++) {
    const int cur = kt8 % 3;
    if (kt8 < 7) {
      stage(kt8 + 1, (kt8 + 1) % 3);
      asm volatile("s_waitcnt vmcnt(4)" ::: "memory");
    } else {
      asm volatile("s_waitcnt vmcnt(0)" ::: "memory");
    }
    __builtin_amdgcn_s_barrier();
    __builtin_amdgcn_sched_barrier(0);
    short8 af[4], bf[4];
#pragma unroll
    for (int m = 0; m < 4; m++) {
      int row = wm + m * 16 + (lane & 15);
      af[m] = *(const short8*)(&As[cur][0] + row * 32 + ((g16 ^ ((row & 3) << 4)) >> 1));
    }
#pragma unroll
    for (int n = 0; n < 4; n++) {
      int row = wn + n * 16 + (lane & 15);
      bf[n] = *(const short8*)(&Bs[cur][0] + row * 32 + ((g16 ^ ((row & 3) << 4)) >> 1));
    }
    __builtin_amdgcn_s_setprio(1);
#pragma unroll
    for (int m = 0; m < 4; m++)
#pragma unroll
      for (int n = 0; n < 4; n++) acc[m][n] = mfma16(af[m], bf[n], acc[m][n]);
    __builtin_amdgcn_s_setprio(0);
  }

#pragma unroll
  for (int m = 0; m < 4; m++)
#pragma unroll
    for (int n = 0; n < 4; n++)
#pragma unroll
      for (int r = 0; r < 4; r++) {
        int row = m0 + wm + m * 16 + ((lane >> 4) << 2) + r;   // channel
        int col = n0 + wn + n * 16 + (lane & 15);              // pixel
        long idx = (long)bz * N_ * C_ + (long)row * N_ + col;
        out[idx] = acc[m][n][r] + bp[row] + x[idx];
      }
}

// ---------------- flash attention: 4 waves, 128 rows, KVBLK=32, skewed pipe ----
// (R8 structure — best measured: 122 µs.)
// LDS: K 16KB single-buffer @0 ; V 2x16KB dbuf @16384 ; 2 blocks/CU.
// Per iter: [bar] stage(it) ; SM(it-1) (hides load latency) ; [bar] ; QK(it)||PV(it-1)
__global__ __launch_bounds__(256, 2) void attn_kernel(
    const short* __restrict__ qT, const short* __restrict__ kT,
    const short* __restrict__ vM, short* __restrict__ P0, short* __restrict__ P1,
    short* __restrict__ P2, short* __restrict__ P3, float2* __restrict__ ml, int S) {
  __shared__ __align__(16) char kv[3 * 16384];
  __shared__ float cbr[4][32];

  const int nwg = 128 * S;                      // 512 at S=4
  const int id = blockIdx.x;
  const int nid = (id & 7) * (nwg >> 3) + (id >> 3);  // XCD-contiguous (bijective, nwg%8==0)
  const int itile = nid & 31;                   // 32 itiles x 128 rows
  const int bjs = nid >> 5;
  const int js = bjs % S;
  const int b = bjs / S;

  const int t = threadIdx.x, lane = t & 63, w = t >> 6;   // w: 0..3
  const int hi = lane >> 5, li = lane & 31;
  const int hi16 = hi * 16;
  const int lsw = li << 4;
  const long bNC = (long)b * N_ * C_;
  const short* qb = qT + bNC;
  const char* kb = (const char*)(kT + bNC);
  const char* vbp = (const char*)(vM + bNC);
  const int i0 = itile * 128 + w * 32;
  const int jbase = js * (N_ / S);
  const int NIT = (N_ / S) / 32;                // 32 when S=4

  // Q b-frags: qf[s] = Q[i0+li][s*16 + hi*8 .. +8]
  short8 qf[16];
  {
    const short* qp = qb + (long)(i0 + li) * C_ + hi * 8;
#pragma unroll
    for (int s = 0; s < 16; s++) qf[s] = *(const short8*)(qp + s * 16);
  }

  f32x16 acco[8];
#pragma unroll
  for (int cb = 0; cb < 8; cb++) acco[cb] = (f32x16)0.f;
  float m_run = -3e38f, l_run = 0.f;

  auto stage = [&](int it, int vb) {
    const int j0 = jbase + it * 32;
    char* Kd = kv;
    char* Vd = kv + 16384 + vb * 16384;
#pragma unroll
    for (int p = 0; p < 4; p++) {
      int flat = p * 4096 + t * 16;
      int rk = flat >> 9;
      int cO = (flat & 511) ^ ((rk & 31) << 4);
      gload16(kb + (long)(j0 + rk) * 512 + cO, Kd + flat);
    }
#pragma unroll
    for (int p = 0; p < 4; p++) {
      int flat = p * 4096 + t * 16;
      int rv = flat >> 9;
      int cO = (flat & 511) ^ ((rv & 31) << 4);
      int c = rv + ((cO >> 6) << 5);
      int off = cO & 63;
      gload16(vbp + (long)c * 8192 + (long)j0 * 2 + off, Vd + flat);
    }
  };

  auto smpack = [&](f32x16& accs, short8& paA, short8& paB) {
    float pm[8];
#pragma unroll
    for (int r = 0; r < 8; r++) pm[r] = fmaxf(accs[2 * r], accs[2 * r + 1]);
#pragma unroll
    for (int r = 0; r < 4; r++) pm[r] = fmaxf(pm[2 * r], pm[2 * r + 1]);
    float pmax = fmaxf(fmaxf(pm[0], pm[1]), fmaxf(pm[2], pm[3]));
    pmax = fmaxf(pmax, __shfl_xor(pmax, 32));
    if (__any(pmax > m_run + THR_)) {
      float mnew = fmaxf(m_run, pmax);
      float corr = exp2f((m_run - mnew) * K2_);
      m_run = mnew;
      l_run *= corr;
      if (lane < 32) cbr[w][li] = corr;
      asm volatile("s_waitcnt lgkmcnt(0)" ::: "memory");
      f32x4 c4[4];
#pragma unroll
      for (int g = 0; g < 4; g++) c4[g] = *(const f32x4*)&cbr[w][g * 8 + hi * 4];
#pragma unroll
      for (int cb = 0; cb < 8; cb++)
#pragma unroll
        for (int r = 0; r < 16; r++) acco[cb][r] *= c4[r >> 2][r & 3];
    }
    const float mk = m_run * K2_;
    float p[16];
#pragma unroll
    for (int r = 0; r < 16; r++) {
      p[r] = exp2f(fmaf(accs[r], K2_, -mk));
      l_run += p[r];
    }
    unsigned a0 = cvtpk(p[0], p[1]), b0 = cvtpk(p[4], p[5]);
    unsigned a1 = cvtpk(p[2], p[3]), b1 = cvtpk(p[6], p[7]);
    plswap(a0, b0); plswap(a1, b1);
    uint4v u0 = {a0, a1, b0, b1};
    paA = __builtin_bit_cast(short8, u0);
    unsigned a2 = cvtpk(p[8], p[9]), b2 = cvtpk(p[12], p[13]);
    unsigned a3 = cvtpk(p[10], p[11]), b3 = cvtpk(p[14], p[15]);
    plswap(a2, b2); plswap(a3, b3);
    uint4v u1 = {a2, a3, b2, b3};
    paB = __builtin_bit_cast(short8, u1);
  };

  const char* Kr = kv + li * 512;

  // prologue: tile 0 into K + V[0]; QK(0)
  stage(0, 0);
  __syncthreads();
  f32x16 accs = (f32x16)0.f;
  __builtin_amdgcn_s_setprio(1);
#pragma unroll
  for (int s = 0; s < 16; s++) {
    short8 kf = *(const short8*)(Kr + ((s * 32 + hi16) ^ lsw));
    accs = mfma32(kf, qf[s], accs);
  }
  __builtin_amdgcn_s_setprio(0);

  short8 pa0, pa1;
  for (int it = 1; it < NIT; it++) {
    __syncthreads();                 // K(it-1) + V(it-2) reads complete block-wide
    stage(it, it & 1);               // K <- tile it ; V[it&1] <- tile it
    smpack(accs, pa0, pa1);          // SM(it-1): rescale acco, pa at scale m(it-1)
    __syncthreads();                 // vmcnt drained -> tile it ready
    const char* Vr = kv + 16384 + ((it - 1) & 1) * 16384 + li * 512;
    f32x16 a2 = (f32x16)0.f;
    __builtin_amdgcn_s_setprio(1);
#pragma unroll
    for (int u = 0; u < 8; u++) {
      short8 kfa = *(const short8*)(Kr + (((2 * u) * 32 + hi16) ^ lsw));
      a2 = mfma32(kfa, qf[2 * u], a2);
      short8 vf0 = *(const short8*)(Vr + ((u * 64 + hi16) ^ lsw));
      acco[u] = mfma32(pa0, vf0, acco[u]);
      short8 kfb = *(const short8*)(Kr + (((2 * u + 1) * 32 + hi16) ^ lsw));
      a2 = mfma32(kfb, qf[2 * u + 1], a2);
      short8 vf1 = *(const short8*)(Vr + ((u * 64 + 32 + hi16) ^ lsw));
      acco[u] = mfma32(pa1, vf1, acco[u]);
    }
    __builtin_amdgcn_s_setprio(0);
    accs = a2;
  }

  // epilogue: SM(NIT-1) + PV(NIT-1)
  smpack(accs, pa0, pa1);
  {
    const char* Vr = kv + 16384 + ((NIT - 1) & 1) * 16384 + li * 512;
    __builtin_amdgcn_s_setprio(1);
#pragma unroll
    for (int cb = 0; cb < 8; cb++) {
      short8 vf0 = *(const short8*)(Vr + ((cb * 64 + hi16) ^ lsw));
      acco[cb] = mfma32(pa0, vf0, acco[cb]);
      short8 vf1 = *(const short8*)(Vr + ((cb * 64 + 32 + hi16) ^ lsw));
      acco[cb] = mfma32(pa1, vf1, acco[cb]);
    }
    __builtin_amdgcn_s_setprio(0);
  }

  // finalize: total l, broadcast 1/l per row, store normalized partial + (m,l)
  l_run += __shfl_xor(l_run, 32);
  float inv = 1.f / l_run;
  if (lane < 32) cbr[w][li] = inv;
  asm volatile("s_waitcnt lgkmcnt(0)" ::: "memory");
  f32x4 i4[4];
#pragma unroll
  for (int g = 0; g < 4; g++) i4[g] = *(const f32x4*)&cbr[w][g * 8 + hi * 4];

  short* Op = (js == 0) ? P0 : (js == 1) ? P1 : (js == 2) ? P2 : P3;
  short* ob = Op + bNC;
#pragma unroll
  for (int cb = 0; cb < 8; cb++)
#pragma unroll
    for (int r = 0; r < 16; r++) {
      int i = i0 + (r & 3) + 8 * (r >> 2) + 4 * hi;
      ob[(long)i * C_ + cb * 32 + li] = f2bf(acco[cb][r] * i4[r >> 2][r & 3]);
    }
  if (lane < 32)
    ml[(long)js * (B_ * N_) + b * N_ + i0 + li] = make_float2(m_run * K2_, l_run);
}

// ---------------- merge the split-j partials ----------------
__global__ __launch_bounds__(256) void combine(const short* __restrict__ p0,
                                               const short* __restrict__ p1,
                                               const short* __restrict__ p2,
                                               const short* __restrict__ p3,
                                               const float2* __restrict__ ml, int S,
                                               short* __restrict__ hT) {
  int idx = blockIdx.x * 256 + threadIdx.x;    // 16384 rows * 32 chunks
  int row = idx >> 5, c0 = (idx & 31) * 8;
  float2 m0 = ml[row], m1 = ml[16384 + row];
  float mmax = fmaxf(m0.x, m1.x);
  float2 m2 = m0, m3 = m0;
  if (S == 4) {
    m2 = ml[2 * 16384 + row];
    m3 = ml[3 * 16384 + row];
    mmax = fmaxf(mmax, fmaxf(m2.x, m3.x));
  }
  float w0 = m0.y * exp2f(m0.x - mmax);
  float w1 = m1.y * exp2f(m1.x - mmax);
  float w2 = 0.f, w3 = 0.f;
  if (S == 4) { w2 = m2.y * exp2f(m2.x - mmax); w3 = m3.y * exp2f(m3.x - mmax); }
  float inv = 1.f / ((w0 + w1) + (w2 + w3));
  w0 *= inv; w1 *= inv; w2 *= inv; w3 *= inv;
  long off = (long)row * 256 + c0;
  short8 u0 = *(const short8*)(p0 + off);
  short8 u1 = *(const short8*)(p1 + off);
  short8 o;
  if (S == 4) {
    short8 u2 = *(const short8*)(p2 + off);
    short8 u3 = *(const short8*)(p3 + off);
#pragma unroll
    for (int j = 0; j < 8; j++)
      o[j] = f2bf((w0 * bf2f(u0[j]) + w1 * bf2f(u1[j])) +
                  (w2 * bf2f(u2[j]) + w3 * bf2f(u3[j])));
  } else {
#pragma unroll
    for (int j = 0; j < 8; j++) o[j] = f2bf(w0 * bf2f(u0[j]) + w1 * bf2f(u1[j]));
  }
  *(short8*)(hT + off) = o;
}

// ---------------- launch ----------------
extern "C" void kernel_launch(void* const* d_in, const int* in_sizes, int n_in,
                              void* d_out, int out_size, void* d_ws, size_t ws_size,
                              hipStream_t stream) {
  const float* x = (const float*)d_in[0];
  const float* gamma = (const float*)d_in[1];
  const float* beta = (const float*)d_in[2];
  const float* wq = (const float*)d_in[3];
  const float* bq = (const float*)d_in[4];
  const float* wk = (const float*)d_in[5];
  const float* bk = (const float*)d_in[6];
  const float* wv = (const float*)d_in[7];
  const float* bv = (const float*)d_in[8];
  const float* wp = (const float*)d_in[9];
  const float* bp = (const float*)d_in[10];

  char* ws = (char*)d_ws;
  short* hn = (short*)ws;                                   // 8MB: hn -> partial0 -> hT
  short* qT = (short*)(ws + (size_t)8388608);
  short* kT = (short*)(ws + (size_t)16777216);
  short* vb = (short*)(ws + (size_t)25165824);
  short* wqkv = (short*)(ws + (size_t)33554432);            // [768][256]
  short* wpb = wqkv + 3 * 65536;                            // [256][256]
  float2* part = (float2*)(ws + (size_t)34078720);          // 256 float2
  float2* ml = (float2*)(ws + (size_t)34080768);            // up to 4*16384 float2
  short* P1 = (short*)d_out;                                // scratch (rewritten by gemm_proj)
  short* P2 = (short*)d_out + 4194304;
  short* P3 = (short*)(ws + (size_t)34605056);
  const int S = (ws_size >= (size_t)43000000) ? 4 : 2;
  if (S == 2) { P2 = hn; P3 = hn; }

  gn_stats1<<<256, 256, 0, stream>>>(x, part);
  gn_norm<<<dim3(16, 16, 4), 256, 0, stream>>>(x, gamma, beta, part, hn);
  cast_w<<<1024, 256, 0, stream>>>(wq, wk, wv, wp, wqkv);

  gemm_qkv<<<dim3(6, 32, 4), 256, 0, stream>>>(hn, wqkv, bq, bk, bv, qT, kT, vb);

  attn_kernel<<<dim3(128 * S), 256, 0, stream>>>(qT, kT, vb, hn /*P0*/, P1, P2, P3, ml, S);
  combine<<<2048, 256, 0, stream>>>(hn, P1, P2, P3, ml, S, hn /*hT in place*/);

  gemm_proj<<<dim3(32, 2, 4), 256, 0, stream>>>(wpb, hn, bp, x, (float*)d_out);
}

// Round 12
// 160.813 us; speedup vs baseline: 1.2589x; 1.0125x over previous
//
#include <hip/hip_runtime.h>

#define B_ 4
#define C_ 256
#define N_ 4096
#define K2_ 0.09016844f   /* 0.0625 * log2(e) */
#define THR_ 64.0f        /* defer-max threshold, raw-score units */

typedef __attribute__((ext_vector_type(8))) short short8;
typedef __attribute__((ext_vector_type(4))) float f32x4;
typedef __attribute__((ext_vector_type(16))) float f32x16;
typedef __attribute__((ext_vector_type(4))) unsigned int uint4v;

static __device__ __forceinline__ short f2bf(float f) {
  union { float f; unsigned u; } v; v.f = f;
  unsigned r = v.u + 0x7FFFu + ((v.u >> 16) & 1u);
  return (short)(r >> 16);
}
static __device__ __forceinline__ float bf2f(short s) {
  union { unsigned u; float f; } v; v.u = ((unsigned)(unsigned short)s) << 16;
  return v.f;
}
static __device__ __forceinline__ f32x4 mfma16(short8 a, short8 b, f32x4 c) {
  return __builtin_amdgcn_mfma_f32_16x16x32_bf16(a, b, c, 0, 0, 0);
}
static __device__ __forceinline__ f32x16 mfma32(short8 a, short8 b, f32x16 c) {
  return __builtin_amdgcn_mfma_f32_32x32x16_bf16(a, b, c, 0, 0, 0);
}
static __device__ __forceinline__ unsigned cvtpk(float lo, float hi) {
  unsigned r;
  asm("v_cvt_pk_bf16_f32 %0, %1, %2" : "=v"(r) : "v"(lo), "v"(hi));
  return r;
}
static __device__ __forceinline__ void plswap(unsigned& a, unsigned& b) {
  asm volatile("v_permlane32_swap_b32 %0, %1" : "+v"(a), "+v"(b));
}
static __device__ __forceinline__ void gload16(const void* g, void* l) {
  __builtin_amdgcn_global_load_lds(
      (const __attribute__((address_space(1))) unsigned int*)g,
      (__attribute__((address_space(3))) unsigned int*)l, 16, 0, 0);
}

// ---------------- GroupNorm stats (blocks 0..255) + weight cast (256..1279) ----
__global__ __launch_bounds__(256) void prep(const float* __restrict__ x,
                                            const float* __restrict__ wq,
                                            const float* __restrict__ wk,
                                            const float* __restrict__ wv,
                                            const float* __restrict__ wp,
                                            float2* __restrict__ part,
                                            short* __restrict__ wout) {
  if (blockIdx.x >= 256) {
    int idx = (blockIdx.x - 256) * 256 + threadIdx.x;   // 4*65536
    int which = idx >> 16, e = idx & 65535;
    const float* src = which == 0 ? wq : which == 1 ? wk : which == 2 ? wv : wp;
    wout[(which << 16) + e] = f2bf(src[e]);
    return;
  }
  int bg = blockIdx.x >> 2, ch = blockIdx.x & 3;
  const float* xp = x + (long)bg * 65536 + ch * 16384;
  int t = threadIdx.x, lane = t & 63, w = t >> 6;
  float s = 0.f, ss = 0.f;
  for (int e = t * 4; e < 16384; e += 1024) {
    f32x4 v = *(const f32x4*)(xp + e);
    s += (v[0] + v[1]) + (v[2] + v[3]);
    ss += (v[0] * v[0] + v[1] * v[1]) + (v[2] * v[2] + v[3] * v[3]);
  }
  for (int off = 1; off < 64; off <<= 1) {
    s += __shfl_xor(s, off);
    ss += __shfl_xor(ss, off);
  }
  __shared__ float rs[4], rq[4];
  if (lane == 0) { rs[w] = s; rq[w] = ss; }
  __syncthreads();
  if (t == 0)
    part[blockIdx.x] = make_float2((rs[0] + rs[1]) + (rs[2] + rs[3]),
                                   (rq[0] + rq[1]) + (rq[2] + rq[3]));
}

// writes hn transposed: hn[b][i][c] bf16
__global__ __launch_bounds__(256) void gn_norm(const float* __restrict__ x,
                                               const float* __restrict__ gamma,
                                               const float* __restrict__ beta,
                                               const float2* __restrict__ part,
                                               short* __restrict__ hn) {
  int ic = blockIdx.x, g = blockIdx.y, b = blockIdx.z;
  int bg = b * 16 + g;
  float2 q0 = part[bg * 4], q1 = part[bg * 4 + 1], q2 = part[bg * 4 + 2], q3 = part[bg * 4 + 3];
  float s = (q0.x + q1.x) + (q2.x + q3.x);
  float ss = (q0.y + q1.y) + (q2.y + q3.y);
  float mean = s * (1.f / 65536.f);
  float rstd = rsqrtf(ss * (1.f / 65536.f) - mean * mean + 1e-6f);
  int t = threadIdx.x;
  int i = ic * 256 + t;
  __shared__ short Ls[16][256];
#pragma unroll
  for (int cl = 0; cl < 16; cl++) {
    int c = g * 16 + cl;
    float v = x[((long)(b * 256 + c)) * N_ + i];
    Ls[cl][t] = f2bf((v - mean) * rstd * gamma[c] + beta[c]);
  }
  __syncthreads();
  short8 v0, v1;
#pragma unroll
  for (int q = 0; q < 8; q++) { v0[q] = Ls[q][t]; v1[q] = Ls[8 + q][t]; }
  short* dst = hn + ((long)b * N_ + ic * 256 + t) * C_ + g * 16;
  *(short8*)dst = v0;
  *(short8*)(dst + 8) = v1;
}

// ---------------- fused QKV GEMM (triple-buffer, counted vmcnt) ----------------
__global__ __launch_bounds__(256) void gemm_qkv(const short* __restrict__ hn,
                                                const short* __restrict__ wqkv,
                                                const float* __restrict__ bq,
                                                const float* __restrict__ bk,
                                                const float* __restrict__ bv,
                                                short* __restrict__ qT,
                                                short* __restrict__ kT,
                                                short* __restrict__ vbM) {
  __shared__ __align__(16) short As[3][128 * 32];
  __shared__ __align__(16) short Bs[3][128 * 32];
  const int bz = blockIdx.z;
  const int n0 = blockIdx.x * 128;   // within 768
  const int m0 = blockIdx.y * 128;   // within 4096
  const int t = threadIdx.x, lane = t & 63, w = t >> 6;
  const int wm = (w >> 1) * 64, wn = (w & 1) * 64;
  const short* Ab = hn + (long)bz * N_ * C_;
  f32x4 acc[4][4];
#pragma unroll
  for (int m = 0; m < 4; m++)
#pragma unroll
    for (int n = 0; n < 4; n++) acc[m][n] = (f32x4)0.f;
  const int g16 = (lane >> 4) * 16;

  auto stage = [&](int kt8, int buf) {
    int kt = kt8 * 32;
#pragma unroll
    for (int s = 0; s < 2; s++) {
      int q = w * 2 + s;
      int flat = q * 1024 + lane * 16;
      int row = flat >> 6, c = flat & 63;
      int cs = c ^ ((row & 3) << 4);
      gload16((const char*)Ab + ((long)(m0 + row) * 256 + kt) * 2 + cs, (char*)As[buf] + flat);
      gload16((const char*)wqkv + ((long)(n0 + row) * 256 + kt) * 2 + cs, (char*)Bs[buf] + flat);
    }
  };

  stage(0, 0);
  for (int kt8 = 0; kt8 < 8; kt8++) {
    const int cur = kt8 % 3;
    if (kt8 < 7) {
      stage(kt8 + 1, (kt8 + 1) % 3);
      asm volatile("s_waitcnt vmcnt(4)" ::: "memory");
    } else {
      asm volatile("s_waitcnt vmcnt(0)" ::: "memory");
    }
    __builtin_amdgcn_s_barrier();
    __builtin_amdgcn_sched_barrier(0);
    short8 af[4], bf[4];
#pragma unroll
    for (int m = 0; m < 4; m++) {
      int row = wm + m * 16 + (lane & 15);
      af[m] = *(const short8*)(&As[cur][0] + row * 32 + ((g16 ^ ((row & 3) << 4)) >> 1));
    }
#pragma unroll
    for (int n = 0; n < 4; n++) {
      int row = wn + n * 16 + (lane & 15);
      bf[n] = *(const short8*)(&Bs[cur][0] + row * 32 + ((g16 ^ ((row & 3) << 4)) >> 1));
    }
    __builtin_amdgcn_s_setprio(1);
#pragma unroll
    for (int m = 0; m < 4; m++)
#pragma unroll
      for (int n = 0; n < 4; n++) acc[m][n] = mfma16(af[m], bf[n], acc[m][n]);
    __builtin_amdgcn_s_setprio(0);
  }

  int seg = n0 >> 8;
  const float* bias = seg == 0 ? bq : seg == 1 ? bk : bv;
#pragma unroll
  for (int m = 0; m < 4; m++)
#pragma unroll
    for (int n = 0; n < 4; n++)
#pragma unroll
      for (int r = 0; r < 4; r++) {
        int row = m0 + wm + m * 16 + ((lane >> 4) << 2) + r;
        int colg = n0 + wn + n * 16 + (lane & 15);
        int coll = colg & 255;
        float vv = acc[m][n][r] + bias[coll];
        if (seg == 2) vbM[(long)bz * N_ * C_ + (long)coll * N_ + row] = f2bf(vv);
        else (seg == 0 ? qT : kT)[(long)bz * N_ * C_ + (long)row * 256 + coll] = f2bf(vv);
      }
}

// ---------------- output projection GEMM (triple-buffer, counted vmcnt) --------
__global__ __launch_bounds__(256) void gemm_proj(const short* __restrict__ wp,
                                                 const short* __restrict__ hT,
                                                 const float* __restrict__ bp,
                                                 const float* __restrict__ x,
                                                 float* __restrict__ out) {
  __shared__ __align__(16) short As[3][128 * 32];
  __shared__ __align__(16) short Bs[3][128 * 32];
  const int bz = blockIdx.z;
  const int n0 = blockIdx.x * 128;   // pixels
  const int m0 = blockIdx.y * 128;   // channels
  const int t = threadIdx.x, lane = t & 63, w = t >> 6;
  const int wm = (w >> 1) * 64, wn = (w & 1) * 64;
  const short* Bb = hT + (long)bz * N_ * C_;
  f32x4 acc[4][4];
#pragma unroll
  for (int m = 0; m < 4; m++)
#pragma unroll
    for (int n = 0; n < 4; n++) acc[m][n] = (f32x4)0.f;
  const int g16 = (lane >> 4) * 16;

  auto stage = [&](int kt8, int buf) {
    int kt = kt8 * 32;
#pragma unroll
    for (int s = 0; s < 2; s++) {
      int q = w * 2 + s;
      int flat = q * 1024 + lane * 16;
      int row = flat >> 6, c = flat & 63;
      int cs = c ^ ((row & 3) << 4);
      gload16((const char*)wp + ((long)(m0 + row) * 256 + kt) * 2 + cs, (char*)As[buf] + flat);
      gload16((const char*)Bb + ((long)(n0 + row) * 256 + kt) * 2 + cs, (char*)Bs[buf] + flat);
    }
  };

  stage(0, 0);
  for (int kt8 = 0; kt8 < 8; kt8++) {
    const int cur = kt8 % 3;
    if (kt8 < 7) {
      stage(kt8 + 1, (kt8 + 1) % 3);
      asm volatile("s_waitcnt vmcnt(4)" ::: "memory");
    } else {
      asm volatile("s_waitcnt vmcnt(0)" ::: "memory");
    }
    __builtin_amdgcn_s_barrier();
    __builtin_amdgcn_sched_barrier(0);
    short8 af[4], bf[4];
#pragma unroll
    for (int m = 0; m < 4; m++) {
      int row = wm + m * 16 + (lane & 15);
      af[m] = *(const short8*)(&As[cur][0] + row * 32 + ((g16 ^ ((row & 3) << 4)) >> 1));
    }
#pragma unroll
    for (int n = 0; n < 4; n++) {
      int row = wn + n * 16 + (lane & 15);
      bf[n] = *(const short8*)(&Bs[cur][0] + row * 32 + ((g16 ^ ((row & 3) << 4)) >> 1));
    }
    __builtin_amdgcn_s_setprio(1);
#pragma unroll
    for (int m = 0; m < 4; m++)
#pragma unroll
      for (int n = 0; n < 4; n++) acc[m][n] = mfma16(af[m], bf[n], acc[m][n]);
    __builtin_amdgcn_s_setprio(0);
  }

#pragma unroll
  for (int m = 0; m < 4; m++)
#pragma unroll
    for (int n = 0; n < 4; n++)
#pragma unroll
      for (int r = 0; r < 4; r++) {
        int row = m0 + wm + m * 16 + ((lane >> 4) << 2) + r;   // channel
        int col = n0 + wn + n * 16 + (lane & 15);              // pixel
        long idx = (long)bz * N_ * C_ + (long)row * N_ + col;
        out[idx] = acc[m][n][r] + bp[row] + x[idx];
      }
}

// ---------------- flash attention: 4 waves, 128 rows, KVBLK=32, skewed pipe ----
// R8 structure + counted vmcnt at barrier2:
//   [__syncthreads] stage(it) ; SM(it-1) ; [vmcnt(4); s_barrier] ; QK(it)||PV(it-1)
// barrier2 needs only K(it) (V(it) first read after NEXT barrier2; V(it-1) drained
// by barrier1's full __syncthreads). V(it)'s 4 loads complete under the compute.
__global__ __launch_bounds__(256, 2) void attn_kernel(
    const short* __restrict__ qT, const short* __restrict__ kT,
    const short* __restrict__ vM, short* __restrict__ P0, short* __restrict__ P1,
    short* __restrict__ P2, short* __restrict__ P3, float2* __restrict__ ml, int S) {
  __shared__ __align__(16) char kv[3 * 16384];
  __shared__ float cbr[4][32];

  const int nwg = 128 * S;                      // 512 at S=4
  const int id = blockIdx.x;
  const int nid = (id & 7) * (nwg >> 3) + (id >> 3);  // XCD-contiguous (bijective, nwg%8==0)
  const int itile = nid & 31;                   // 32 itiles x 128 rows
  const int bjs = nid >> 5;
  const int js = bjs % S;
  const int b = bjs / S;

  const int t = threadIdx.x, lane = t & 63, w = t >> 6;   // w: 0..3
  const int hi = lane >> 5, li = lane & 31;
  const int hi16 = hi * 16;
  const int lsw = li << 4;
  const long bNC = (long)b * N_ * C_;
  const short* qb = qT + bNC;
  const char* kb = (const char*)(kT + bNC);
  const char* vbp = (const char*)(vM + bNC);
  const int i0 = itile * 128 + w * 32;
  const int jbase = js * (N_ / S);
  const int NIT = (N_ / S) / 32;                // 32 when S=4

  // Q b-frags: qf[s] = Q[i0+li][s*16 + hi*8 .. +8]
  short8 qf[16];
  {
    const short* qp = qb + (long)(i0 + li) * C_ + hi * 8;
#pragma unroll
    for (int s = 0; s < 16; s++) qf[s] = *(const short8*)(qp + s * 16);
  }

  f32x16 acco[8];
#pragma unroll
  for (int cb = 0; cb < 8; cb++) acco[cb] = (f32x16)0.f;
  float m_run = -3e38f, l_run = 0.f;

  auto stage = [&](int it, int vb) {
    const int j0 = jbase + it * 32;
    char* Kd = kv;
    char* Vd = kv + 16384 + vb * 16384;
#pragma unroll
    for (int p = 0; p < 4; p++) {
      int flat = p * 4096 + t * 16;
      int rk = flat >> 9;
      int cO = (flat & 511) ^ ((rk & 31) << 4);
      gload16(kb + (long)(j0 + rk) * 512 + cO, Kd + flat);
    }
#pragma unroll
    for (int p = 0; p < 4; p++) {
      int flat = p * 4096 + t * 16;
      int rv = flat >> 9;
      int cO = (flat & 511) ^ ((rv & 31) << 4);
      int c = rv + ((cO >> 6) << 5);
      int off = cO & 63;
      gload16(vbp + (long)c * 8192 + (long)j0 * 2 + off, Vd + flat);
    }
  };

  auto smpack = [&](f32x16& accs, short8& paA, short8& paB) {
    float pm[8];
#pragma unroll
    for (int r = 0; r < 8; r++) pm[r] = fmaxf(accs[2 * r], accs[2 * r + 1]);
#pragma unroll
    for (int r = 0; r < 4; r++) pm[r] = fmaxf(pm[2 * r], pm[2 * r + 1]);
    float pmax = fmaxf(fmaxf(pm[0], pm[1]), fmaxf(pm[2], pm[3]));
    pmax = fmaxf(pmax, __shfl_xor(pmax, 32));
    if (__any(pmax > m_run + THR_)) {
      float mnew = fmaxf(m_run, pmax);
      float corr = exp2f((m_run - mnew) * K2_);
      m_run = mnew;
      l_run *= corr;
      if (lane < 32) cbr[w][li] = corr;
      asm volatile("s_waitcnt lgkmcnt(0)" ::: "memory");
      f32x4 c4[4];
#pragma unroll
      for (int g = 0; g < 4; g++) c4[g] = *(const f32x4*)&cbr[w][g * 8 + hi * 4];
#pragma unroll
      for (int cb = 0; cb < 8; cb++)
#pragma unroll
        for (int r = 0; r < 16; r++) acco[cb][r] *= c4[r >> 2][r & 3];
    }
    const float mk = m_run * K2_;
    float p[16];
#pragma unroll
    for (int r = 0; r < 16; r++) {
      p[r] = exp2f(fmaf(accs[r], K2_, -mk));
      l_run += p[r];
    }
    unsigned a0 = cvtpk(p[0], p[1]), b0 = cvtpk(p[4], p[5]);
    unsigned a1 = cvtpk(p[2], p[3]), b1 = cvtpk(p[6], p[7]);
    plswap(a0, b0); plswap(a1, b1);
    uint4v u0 = {a0, a1, b0, b1};
    paA = __builtin_bit_cast(short8, u0);
    unsigned a2 = cvtpk(p[8], p[9]), b2 = cvtpk(p[12], p[13]);
    unsigned a3 = cvtpk(p[10], p[11]), b3 = cvtpk(p[14], p[15]);
    plswap(a2, b2); plswap(a3, b3);
    uint4v u1 = {a2, a3, b2, b3};
    paB = __builtin_bit_cast(short8, u1);
  };

  const char* Kr = kv + li * 512;

  // prologue: tile 0 into K + V[0]; QK(0)
  stage(0, 0);
  __syncthreads();
  f32x16 accs = (f32x16)0.f;
  __builtin_amdgcn_s_setprio(1);
#pragma unroll
  for (int s = 0; s < 16; s++) {
    short8 kf = *(const short8*)(Kr + ((s * 32 + hi16) ^ lsw));
    accs = mfma32(kf, qf[s], accs);
  }
  __builtin_amdgcn_s_setprio(0);

  short8 pa0, pa1;
  for (int it = 1; it < NIT; it++) {
    __syncthreads();                 // K(it-1)+V(it-2) reads done; V(it-1) drained
    stage(it, it & 1);               // K <- tile it ; V[it&1] <- tile it
    smpack(accs, pa0, pa1);          // SM(it-1): rescale acco, pa at scale m(it-1)
    asm volatile("s_waitcnt vmcnt(4)" ::: "memory");  // K(it) done; V(it) in flight
    __builtin_amdgcn_s_barrier();    // all waves' K(it) visible
    const char* Vr = kv + 16384 + ((it - 1) & 1) * 16384 + li * 512;
    f32x16 a2 = (f32x16)0.f;
    __builtin_amdgcn_s_setprio(1);
#pragma unroll
    for (int u = 0; u < 8; u++) {
      short8 kfa = *(const short8*)(Kr + (((2 * u) * 32 + hi16) ^ lsw));
      a2 = mfma32(kfa, qf[2 * u], a2);
      short8 vf0 = *(const short8*)(Vr + ((u * 64 + hi16) ^ lsw));
      acco[u] = mfma32(pa0, vf0, acco[u]);
      short8 kfb = *(const short8*)(Kr + (((2 * u + 1) * 32 + hi16) ^ lsw));
      a2 = mfma32(kfb, qf[2 * u + 1], a2);
      short8 vf1 = *(const short8*)(Vr + ((u * 64 + 32 + hi16) ^ lsw));
      acco[u] = mfma32(pa1, vf1, acco[u]);
    }
    __builtin_amdgcn_s_setprio(0);
    accs = a2;
  }

  // epilogue: SM(NIT-1); drain V(NIT-1); PV(NIT-1)
  smpack(accs, pa0, pa1);
  asm volatile("s_waitcnt vmcnt(0)" ::: "memory");
  __builtin_amdgcn_s_barrier();
  {
    const char* Vr = kv + 16384 + ((NIT - 1) & 1) * 16384 + li * 512;
    __builtin_amdgcn_s_setprio(1);
#pragma unroll
    for (int cb = 0; cb < 8; cb++) {
      short8 vf0 = *(const short8*)(Vr + ((cb * 64 + hi16) ^ lsw));
      acco[cb] = mfma32(pa0, vf0, acco[cb]);
      short8 vf1 = *(const short8*)(Vr + ((cb * 64 + 32 + hi16) ^ lsw));
      acco[cb] = mfma32(pa1, vf1, acco[cb]);
    }
    __builtin_amdgcn_s_setprio(0);
  }

  // finalize: total l, broadcast 1/l per row, store normalized partial + (m,l)
  l_run += __shfl_xor(l_run, 32);
  float inv = 1.f / l_run;
  if (lane < 32) cbr[w][li] = inv;
  asm volatile("s_waitcnt lgkmcnt(0)" ::: "memory");
  f32x4 i4[4];
#pragma unroll
  for (int g = 0; g < 4; g++) i4[g] = *(const f32x4*)&cbr[w][g * 8 + hi * 4];

  short* Op = (js == 0) ? P0 : (js == 1) ? P1 : (js == 2) ? P2 : P3;
  short* ob = Op + bNC;
#pragma unroll
  for (int cb = 0; cb < 8; cb++)
#pragma unroll
    for (int r = 0; r < 16; r++) {
      int i = i0 + (r & 3) + 8 * (r >> 2) + 4 * hi;
      ob[(long)i * C_ + cb * 32 + li] = f2bf(acco[cb][r] * i4[r >> 2][r & 3]);
    }
  if (lane < 32)
    ml[(long)js * (B_ * N_) + b * N_ + i0 + li] = make_float2(m_run * K2_, l_run);
}

// ---------------- merge the split-j partials ----------------
__global__ __launch_bounds__(256) void combine(const short* __restrict__ p0,
                                               const short* __restrict__ p1,
                                               const short* __restrict__ p2,
                                               const short* __restrict__ p3,
                                               const float2* __restrict__ ml, int S,
                                               short* __restrict__ hT) {
  int idx = blockIdx.x * 256 + threadIdx.x;    // 16384 rows * 32 chunks
  int row = idx >> 5, c0 = (idx & 31) * 8;
  float2 m0 = ml[row], m1 = ml[16384 + row];
  float mmax = fmaxf(m0.x, m1.x);
  float2 m2 = m0, m3 = m0;
  if (S == 4) {
    m2 = ml[2 * 16384 + row];
    m3 = ml[3 * 16384 + row];
    mmax = fmaxf(mmax, fmaxf(m2.x, m3.x));
  }
  float w0 = m0.y * exp2f(m0.x - mmax);
  float w1 = m1.y * exp2f(m1.x - mmax);
  float w2 = 0.f, w3 = 0.f;
  if (S == 4) { w2 = m2.y * exp2f(m2.x - mmax); w3 = m3.y * exp2f(m3.x - mmax); }
  float inv = 1.f / ((w0 + w1) + (w2 + w3));
  w0 *= inv; w1 *= inv; w2 *= inv; w3 *= inv;
  long off = (long)row * 256 + c0;
  short8 u0 = *(const short8*)(p0 + off);
  short8 u1 = *(const short8*)(p1 + off);
  short8 o;
  if (S == 4) {
    short8 u2 = *(const short8*)(p2 + off);
    short8 u3 = *(const short8*)(p3 + off);
#pragma unroll
    for (int j = 0; j < 8; j++)
      o[j] = f2bf((w0 * bf2f(u0[j]) + w1 * bf2f(u1[j])) +
                  (w2 * bf2f(u2[j]) + w3 * bf2f(u3[j])));
  } else {
#pragma unroll
    for (int j = 0; j < 8; j++) o[j] = f2bf(w0 * bf2f(u0[j]) + w1 * bf2f(u1[j]));
  }
  *(short8*)(hT + off) = o;
}

// ---------------- launch ----------------
extern "C" void kernel_launch(void* const* d_in, const int* in_sizes, int n_in,
                              void* d_out, int out_size, void* d_ws, size_t ws_size,
                              hipStream_t stream) {
  const float* x = (const float*)d_in[0];
  const float* gamma = (const float*)d_in[1];
  const float* beta = (const float*)d_in[2];
  const float* wq = (const float*)d_in[3];
  const float* bq = (const float*)d_in[4];
  const float* wk = (const float*)d_in[5];
  const float* bk = (const float*)d_in[6];
  const float* wv = (const float*)d_in[7];
  const float* bv = (const float*)d_in[8];
  const float* wp = (const float*)d_in[9];
  const float* bp = (const float*)d_in[10];

  char* ws = (char*)d_ws;
  short* hn = (short*)ws;                                   // 8MB: hn -> partial0 -> hT
  short* qT = (short*)(ws + (size_t)8388608);
  short* kT = (short*)(ws + (size_t)16777216);
  short* vb = (short*)(ws + (size_t)25165824);
  short* wqkv = (short*)(ws + (size_t)33554432);            // [768][256]
  short* wpb = wqkv + 3 * 65536;                            // [256][256]
  float2* part = (float2*)(ws + (size_t)34078720);          // 256 float2
  float2* ml = (float2*)(ws + (size_t)34080768);            // up to 4*16384 float2
  short* P1 = (short*)d_out;                                // scratch (rewritten by gemm_proj)
  short* P2 = (short*)d_out + 4194304;
  short* P3 = (short*)(ws + (size_t)34605056);
  const int S = (ws_size >= (size_t)43000000) ? 4 : 2;
  if (S == 2) { P2 = hn; P3 = hn; }

  prep<<<1280, 256, 0, stream>>>(x, wq, wk, wv, wp, part, wqkv);
  gn_norm<<<dim3(16, 16, 4), 256, 0, stream>>>(x, gamma, beta, part, hn);

  gemm_qkv<<<dim3(6, 32, 4), 256, 0, stream>>>(hn, wqkv, bq, bk, bv, qT, kT, vb);

  attn_kernel<<<dim3(128 * S), 256, 0, stream>>>(qT, kT, vb, hn /*P0*/, P1, P2, P3, ml, S);
  combine<<<2048, 256, 0, stream>>>(hn, P1, P2, P3, ml, S, hn /*hT in place*/);

  gemm_proj<<<dim3(32, 2, 4), 256, 0, stream>>>(wpb, hn, bp, x, (float*)d_out);
}